// Round 8
// baseline (953.593 us; speedup 1.0000x reference)
//
#include <hip/hip_runtime.h>
#include <hip/hip_bf16.h>

// TransducerJoint: h[b,t,u,:] = f[b,t,:] + g[b,u,:] when t<f_len[b] && u<g_len[b], else 0.
// B=16, T=256, U=96, H=512, fp32. Write-bound: 805 MB out, ~11 MB in.
//
// MEASUREMENT ROUND: rounds 1/5/7 (three very different structures) all
// measured 780-806 us, and the top-5 dispatches are all ~510us 3-GiB harness
// poison fills -> dur_us includes fixed poison overhead; kernel time unknown
// (~156us at-roofline vs ~284us with-headroom both fit the data).
// This round launches the SAME kernel TWICE (idempotent, same work each call):
// delta vs round 7's 794us isolates one kernel duration cleanly.

#define TJ_B 16
#define TJ_T 256
#define TJ_U 96
#define TJ_H4 128            // H/4 fx4 per row
#define TJ_TT 2              // t-rows per block
#define TJ_NTH 512           // threads per block
#define TJ_K ((TJ_U * TJ_H4) / TJ_NTH)   // 24 g-quads per thread

typedef float fx4 __attribute__((ext_vector_type(4)));

__global__ __launch_bounds__(TJ_NTH) void TransducerJoint_66915590472509_kernel(
    const fx4* __restrict__ f,      // (B, T, H/4)
    const fx4* __restrict__ g,      // (B, U, H/4)
    const int* __restrict__ f_len,  // (B,)
    const int* __restrict__ g_len,  // (B,)
    fx4* __restrict__ out)          // (B, T, U, H/4)
{
    const int bid = blockIdx.x;              // b*(T/TT) + tchunk
    const int b   = bid >> 7;                // T/TT = 128
    const int t0  = (bid & 127) * TJ_TT;
    const int i   = threadIdx.x;             // 0..511
    const int h4  = i & (TJ_H4 - 1);         // f fragment index (const across k)
    const int uu  = i >> 7;                  // base u offset: u_k = uu + 4k

    const int flen = f_len[b];
    const int glen = g_len[b];

    // ---- load phase ----
    fx4 fr[TJ_TT];
    #pragma unroll
    for (int tt = 0; tt < TJ_TT; ++tt)
        fr[tt] = f[(size_t)(b * TJ_T + t0 + tt) * TJ_H4 + h4];

    fx4 gr[TJ_K];
    const fx4* gb = g + (size_t)b * (TJ_U * TJ_H4);
    #pragma unroll
    for (int k = 0; k < TJ_K; ++k)
        gr[k] = gb[i + TJ_NTH * k];          // whole g[b], wave-coalesced

    // ---- pure store phase ----
    #pragma unroll
    for (int tt = 0; tt < TJ_TT; ++tt) {
        const int t = t0 + tt;
        const bool tok = (t < flen);         // block-uniform
        const fx4 fv = fr[tt];
        fx4* op = out + (size_t)(b * TJ_T + t) * (TJ_U * TJ_H4) + i;
        #pragma unroll
        for (int k = 0; k < TJ_K; ++k) {
            const bool ok = tok && ((uu + 4 * k) < glen);
            op[TJ_NTH * k] = ok ? (fv + gr[k]) : (fx4)0.f;
        }
    }
}

extern "C" void kernel_launch(void* const* d_in, const int* in_sizes, int n_in,
                              void* d_out, int out_size, void* d_ws, size_t ws_size,
                              hipStream_t stream) {
    const fx4* f     = (const fx4*)d_in[0];
    const fx4* g     = (const fx4*)d_in[1];
    const int* f_len = (const int*)d_in[2];
    const int* g_len = (const int*)d_in[3];
    fx4*       out   = (fx4*)d_out;

    const int nblocks = TJ_B * (TJ_T / TJ_TT);   // 2048
    // Launch TWICE: second pass rewrites identical values (idempotent).
    // dur_us(this round) - dur_us(round 7) == one kernel's true duration.
    TransducerJoint_66915590472509_kernel<<<nblocks, TJ_NTH, 0, stream>>>(
        f, g, f_len, g_len, out);
    TransducerJoint_66915590472509_kernel<<<nblocks, TJ_NTH, 0, stream>>>(
        f, g, f_len, g_len, out);
}

// Round 9
// 796.240 us; speedup vs baseline: 1.1976x; 1.1976x over previous
//
#include <hip/hip_runtime.h>
#include <hip/hip_bf16.h>

// TransducerJoint: h[b,t,u,:] = f[b,t,:] + g[b,u,:] when t<f_len[b] && u<g_len[b], else 0.
// B=16, T=256, U=96, H=512, fp32. 805 MB written, ~11 MB read.
//
// Round-8 measurement (double-launch delta): kernel = 159.5 us = 5.05 TB/s vs
// 6.29 TB/s the harness fill achieves on this same buffer (=> ~130 us floor).
// Fill saturates at ~10% occupancy -> store BW needs few waves; the gap is
// store-stream GAPS: 4 discrete block-rounds, each starting with a ~26-load
// phase with no stores in flight. Fix: persistent pipelined kernel.
//   grid = 512 blocks x 512 thr (2/CU, ALL resident, one round).
//   Each block: one b (bid>>5), 12 chunks = 4 t-pairs x 3 u-thirds.
//   Loads for chunk c+1 issue BEFORE stores of chunk c (loads older in the
//   vmcnt FIFO -> their wait never forces store drain). Steady state =
//   continuous stores; one startup stall per block only.
// Double-buffer regs indexed by (c&1) under a fully-unrolled c-loop ->
// compile-time indices, stays in registers (rule #20).

#define TJ_T 256
#define TJ_U 96
#define TJ_H4 128            // H/4 fx4 per row
#define TJ_ROW (TJ_U * TJ_H4)   // 12288 fx4 per (b,t) row

typedef float fx4 __attribute__((ext_vector_type(4)));

__global__ __launch_bounds__(512) void TransducerJoint_66915590472509_kernel(
    const fx4* __restrict__ f,      // (B, T, H/4)
    const fx4* __restrict__ g,      // (B, U, H/4)
    const int* __restrict__ f_len,  // (B,)
    const int* __restrict__ g_len,  // (B,)
    fx4* __restrict__ out)          // (B, T, U, H/4)
{
    const int bid = blockIdx.x;          // 0..511
    const int b   = bid >> 5;            // 32 blocks per b
    const int tc0 = (bid & 31) << 2;     // first t-pair; block covers t-pairs tc0..tc0+3
    const int i   = threadIdx.x;         // 0..511
    const int h4  = i & (TJ_H4 - 1);
    const int uu  = i >> 7;              // 0..3

    const int flen = f_len[b];
    const int glen = g_len[b];

    const fx4* fb = f + (size_t)b * TJ_T * TJ_H4;
    const fx4* gb = g + (size_t)b * TJ_ROW;
    fx4*       ob = out + (size_t)b * TJ_T * TJ_ROW;

    fx4 ga[2][8];    // g third: u = r*32 + uu + 4k, k=0..7
    fx4 fa[2][2];    // 2 f rows of the t-pair

    // chunk c (0..11): j = c/3 (t-pair), r = c%3 (u-third) — compile-time under unroll.
    #define TJ_LOADC(buf, c)                                                  \
        do {                                                                  \
            constexpr int j_ = (c) / 3, r_ = (c) - 3 * ((c) / 3);             \
            const int t0_ = (tc0 + j_) * 2;                                   \
            fa[buf][0] = fb[(t0_ + 0) * TJ_H4 + h4];                          \
            fa[buf][1] = fb[(t0_ + 1) * TJ_H4 + h4];                          \
            _Pragma("unroll")                                                 \
            for (int k = 0; k < 8; ++k)                                       \
                ga[buf][k] = gb[r_ * 4096 + i + 512 * k];                     \
        } while (0)

    #define TJ_STOREC(buf, c)                                                 \
        do {                                                                  \
            constexpr int j_ = (c) / 3, r_ = (c) - 3 * ((c) / 3);             \
            const int t0_ = (tc0 + j_) * 2;                                   \
            _Pragma("unroll")                                                 \
            for (int tt = 0; tt < 2; ++tt) {                                  \
                const bool tok_ = (t0_ + tt) < flen;                          \
                const fx4 fv_ = fa[buf][tt];                                  \
                fx4* op_ = ob + (size_t)(t0_ + tt) * TJ_ROW + r_ * 4096 + i;  \
                _Pragma("unroll")                                             \
                for (int k = 0; k < 8; ++k) {                                 \
                    const bool ok_ = tok_ && (r_ * 32 + uu + 4 * k) < glen;   \
                    op_[512 * k] = ok_ ? (fv_ + ga[buf][k]) : (fx4)0.f;       \
                }                                                             \
            }                                                                 \
        } while (0)

    TJ_LOADC(0, 0);
    #pragma unroll
    for (int c = 0; c < 12; ++c) {
        // issue next chunk's loads BEFORE this chunk's stores (loads stay
        // oldest in the vmcnt FIFO -> load-waits never drain stores)
        switch (c + 1) {   // compile-time per unrolled iteration
            case 1:  TJ_LOADC(1, 1);  break;
            case 2:  TJ_LOADC(0, 2);  break;
            case 3:  TJ_LOADC(1, 3);  break;
            case 4:  TJ_LOADC(0, 4);  break;
            case 5:  TJ_LOADC(1, 5);  break;
            case 6:  TJ_LOADC(0, 6);  break;
            case 7:  TJ_LOADC(1, 7);  break;
            case 8:  TJ_LOADC(0, 8);  break;
            case 9:  TJ_LOADC(1, 9);  break;
            case 10: TJ_LOADC(0, 10); break;
            case 11: TJ_LOADC(1, 11); break;
            default: break;
        }
        switch (c) {
            case 0:  TJ_STOREC(0, 0);  break;
            case 1:  TJ_STOREC(1, 1);  break;
            case 2:  TJ_STOREC(0, 2);  break;
            case 3:  TJ_STOREC(1, 3);  break;
            case 4:  TJ_STOREC(0, 4);  break;
            case 5:  TJ_STOREC(1, 5);  break;
            case 6:  TJ_STOREC(0, 6);  break;
            case 7:  TJ_STOREC(1, 7);  break;
            case 8:  TJ_STOREC(0, 8);  break;
            case 9:  TJ_STOREC(1, 9);  break;
            case 10: TJ_STOREC(0, 10); break;
            case 11: TJ_STOREC(1, 11); break;
        }
    }
}

extern "C" void kernel_launch(void* const* d_in, const int* in_sizes, int n_in,
                              void* d_out, int out_size, void* d_ws, size_t ws_size,
                              hipStream_t stream) {
    const fx4* f     = (const fx4*)d_in[0];
    const fx4* g     = (const fx4*)d_in[1];
    const int* f_len = (const int*)d_in[2];
    const int* g_len = (const int*)d_in[3];
    fx4*       out   = (fx4*)d_out;

    TransducerJoint_66915590472509_kernel<<<512, 512, 0, stream>>>(
        f, g, f_len, g_len, out);
}